// Round 2
// baseline (434.742 us; speedup 1.0000x reference)
//
#include <hip/hip_runtime.h>

#define S_DEPTH 256
#define NRES 384
#define CIN 32
#define CZ 128
#define MDIM (NRES * CIN) /* 12288 */

typedef short bf16x8 __attribute__((ext_vector_type(8)));
typedef short short4v __attribute__((ext_vector_type(4)));
typedef float f32x4 __attribute__((ext_vector_type(4)));

static __device__ __forceinline__ unsigned short f2bf(float f) {
  unsigned int u = __float_as_uint(f);
  unsigned int r = (u + 0x7fffu + ((u >> 16) & 1u)) >> 16; // RNE
  return (unsigned short)r;
}

// ---------------- kernel 0: W3 -> bf16, layout W3T[e][d*32 + c] ----------------
__global__ __launch_bounds__(256) void k_w3t(const float* __restrict__ W3,
                                             unsigned short* __restrict__ W3T) {
  int t = blockIdx.x * 256 + threadIdx.x; // 0..131071
  int e = t >> 10;
  int q = t & 1023;    // q' = d*32 + c
  int d = q >> 5, c = q & 31;
  W3T[t] = f2bf(W3[(c * 32 + d) * 128 + e]);
}

// ---------------- kernel 1: LayerNorm + W1/W2 proj -> aT, bT (bf16, [m][k=s]) ----
__global__ __launch_bounds__(256) void k_lnproj(
    const float* __restrict__ mm, const float* __restrict__ gamma,
    const float* __restrict__ beta, const float* __restrict__ W1,
    const float* __restrict__ W2, unsigned short* __restrict__ aT,
    unsigned short* __restrict__ bT) {
  __shared__ float buf[256 * 33]; // stride 33 to break bank alignment
  const int t = threadIdx.x;
  const int i = blockIdx.x;

  // stage m[s][i][0:32] for all s, coalesced 16B per lane
#pragma unroll
  for (int it = 0; it < 8; ++it) {
    int s = it * 32 + (t >> 3);
    int c4 = (t & 7) * 4;
    const float4 v = *(const float4*)(mm + ((size_t)s * NRES + i) * CIN + c4);
    buf[s * 33 + c4 + 0] = v.x;
    buf[s * 33 + c4 + 1] = v.y;
    buf[s * 33 + c4 + 2] = v.z;
    buf[s * 33 + c4 + 3] = v.w;
  }
  __syncthreads();

  // thread t owns MSA row s = t
  float x[32];
#pragma unroll
  for (int k = 0; k < 32; ++k) x[k] = buf[t * 33 + k];
  float mu = 0.f;
#pragma unroll
  for (int k = 0; k < 32; ++k) mu += x[k];
  mu *= (1.f / 32.f);
  float var = 0.f;
#pragma unroll
  for (int k = 0; k < 32; ++k) {
    float dk = x[k] - mu;
    var += dk * dk;
  }
  var *= (1.f / 32.f);
  float inv = rsqrtf(var + 1e-5f);
#pragma unroll
  for (int k = 0; k < 32; ++k) x[k] = (x[k] - mu) * inv * gamma[k] + beta[k];

  float va[32], vb[32];
#pragma unroll
  for (int c = 0; c < 32; ++c) {
    float sa = 0.f, sb = 0.f;
#pragma unroll
    for (int k = 0; k < 32; ++k) {
      sa += x[k] * W1[k * 32 + c]; // uniform -> s_load
      sb += x[k] * W2[k * 32 + c];
    }
    va[c] = sa;
    vb[c] = sb;
  }

  // transpose via LDS, write aT then bT: row (i*32+c), 256 k-contiguous bf16
  __syncthreads();
#pragma unroll
  for (int c = 0; c < 32; ++c) buf[t * 33 + c] = va[c];
  __syncthreads();
  {
    unsigned short* dst = aT + (size_t)i * 32 * 256;
#pragma unroll
    for (int rrep = 0; rrep < 4; ++rrep) {
      int id = rrep * 256 + t;
      int c = id >> 5, s8 = (id & 31) * 8;
      union { unsigned short us[8]; uint4 v; } pk;
#pragma unroll
      for (int j2 = 0; j2 < 8; ++j2) pk.us[j2] = f2bf(buf[(s8 + j2) * 33 + c]);
      *(uint4*)(dst + c * 256 + s8) = pk.v;
    }
  }
  __syncthreads();
#pragma unroll
  for (int c = 0; c < 32; ++c) buf[t * 33 + c] = vb[c];
  __syncthreads();
  {
    unsigned short* dst = bT + (size_t)i * 32 * 256;
#pragma unroll
    for (int rrep = 0; rrep < 4; ++rrep) {
      int id = rrep * 256 + t;
      int c = id >> 5, s8 = (id & 31) * 8;
      union { unsigned short us[8]; uint4 v; } pk;
#pragma unroll
      for (int j2 = 0; j2 < 8; ++j2) pk.us[j2] = f2bf(buf[(s8 + j2) * 33 + c]);
      *(uint4*)(dst + c * 256 + s8) = pk.v;
    }
  }
}

// ---------------- kernel 2: fused o-GEMM (128x256 tile, K=256) + W3 epilogue ----
// Main loop: NO LDS, NO barriers — A/B fragments stream directly from global
// (L2-hot) into registers; compiler pipelines loads vs MFMA with vmcnt(N).
// LDS (64 KB) is used only for the o-repack before the W3 epilogue GEMM.
__global__ __launch_bounds__(256, 2) void k_opm(
    const unsigned short* __restrict__ aT, const unsigned short* __restrict__ bT,
    const unsigned short* __restrict__ W3T, const float* __restrict__ b3,
    float* __restrict__ out) {
  __shared__ __align__(16) char smem[65536];
  const int t = threadIdx.x;
  const int w = t >> 6;      // wave 0..3
  const int l = t & 63;      // lane
  const int lr = l & 15;
  const int quad = l >> 4;
  const int wm = w >> 1, wn = w & 1; // wave tile: rows wm*64, cols wn*128
  const int m0 = blockIdx.y * 128;   // i-block (4 residues)
  const int n0 = blockIdx.x * 256;   // j-block (8 residues)

  f32x4 acc[4][8];
#pragma unroll
  for (int mt = 0; mt < 4; ++mt)
#pragma unroll
    for (int nt = 0; nt < 8; ++nt) {
      acc[mt][nt][0] = 0.f; acc[mt][nt][1] = 0.f;
      acc[mt][nt][2] = 0.f; acc[mt][nt][3] = 0.f;
    }

  // A-frag for 16x16x32 MFMA: A[m = lane&15][k = quad*8 + j]
  const unsigned short* aBase = aT + (size_t)(m0 + wm * 64 + lr) * 256 + quad * 8;
  const unsigned short* bBase = bT + (size_t)(n0 + wn * 128 + lr) * 256 + quad * 8;

#pragma unroll
  for (int k0 = 0; k0 < 256; k0 += 32) {
    bf16x8 af[4], bfr[8];
#pragma unroll
    for (int mt = 0; mt < 4; ++mt)
      af[mt] = *(const bf16x8*)(aBase + (size_t)mt * 16 * 256 + k0);
#pragma unroll
    for (int nt = 0; nt < 8; ++nt)
      bfr[nt] = *(const bf16x8*)(bBase + (size_t)nt * 16 * 256 + k0);
#pragma unroll
    for (int nt = 0; nt < 8; ++nt)
#pragma unroll
      for (int mt = 0; mt < 4; ++mt)
        acc[mt][nt] =
            __builtin_amdgcn_mfma_f32_16x16x32_bf16(af[mt], bfr[nt], acc[mt][nt], 0, 0, 0);
  }

  // ---- epilogue: repack o (bf16, /256) into o_lds[32 pairs][1024 q'] with
  // XOR chunk swizzle key=(p^d)&7 -> reads & writes <=2-way conflicts ----
  // (no barrier needed before: smem untouched until here, waves write disjoint p)
  const float scale = 1.0f / 256.0f;
#pragma unroll
  for (int mt = 0; mt < 4; ++mt) {
    int i_l = wm * 2 + (mt >> 1);
    int chc = 2 * (mt & 1) + (quad >> 1); // (c0>>3)
#pragma unroll
    for (int nt = 0; nt < 8; ++nt) {
      int j_l = wn * 4 + (nt >> 1);
      int d = (nt & 1) * 16 + lr;
      int p = i_l * 8 + j_l;
      int ch = d * 4 + chc;
      int key = (p ^ d) & 7;
      int off = p * 2048 + ((ch ^ key) << 4) + 8 * (quad & 1); // bytes
      short4v pk;
      pk[0] = (short)f2bf(acc[mt][nt][0] * scale);
      pk[1] = (short)f2bf(acc[mt][nt][1] * scale);
      pk[2] = (short)f2bf(acc[mt][nt][2] * scale);
      pk[3] = (short)f2bf(acc[mt][nt][3] * scale);
      *(short4v*)(smem + off) = pk;
    }
  }
  __syncthreads();

  // ---- z[p][e] = sum_q o[p][q'] * W3T[e][q'] ; wave w owns e-tiles {2w,2w+1}
  f32x4 zacc[2][2];
#pragma unroll
  for (int a = 0; a < 2; ++a)
#pragma unroll
    for (int b = 0; b < 2; ++b) {
      zacc[a][b][0] = 0.f; zacc[a][b][1] = 0.f;
      zacc[a][b][2] = 0.f; zacc[a][b][3] = 0.f;
    }
  float bias0 = b3[(w * 2 + 0) * 16 + lr];
  float bias1 = b3[(w * 2 + 1) * 16 + lr];

#pragma unroll 4
  for (int kq = 0; kq < 32; ++kq) {
    bf16x8 aef[2];
#pragma unroll
    for (int mte = 0; mte < 2; ++mte) {
      int row = mte * 16 + lr;
      int ch = kq * 4 + quad;
      int key = (row ^ kq) & 7;
      aef[mte] = *(const bf16x8*)(smem + row * 2048 + ((ch ^ key) << 4));
    }
#pragma unroll
    for (int nte = 0; nte < 2; ++nte) {
      const unsigned short* wg =
          W3T + (size_t)((w * 2 + nte) * 16 + lr) * 1024 + kq * 32 + quad * 8;
      bf16x8 bfr = *(const bf16x8*)wg;
#pragma unroll
      for (int mte = 0; mte < 2; ++mte)
        zacc[mte][nte] =
            __builtin_amdgcn_mfma_f32_16x16x32_bf16(aef[mte], bfr, zacc[mte][nte], 0, 0, 0);
    }
  }

  const int i0 = blockIdx.y * 4, j0 = blockIdx.x * 8;
#pragma unroll
  for (int mte = 0; mte < 2; ++mte)
#pragma unroll
    for (int nte = 0; nte < 2; ++nte) {
      int e = (w * 2 + nte) * 16 + lr;
      float bias = nte ? bias1 : bias0;
#pragma unroll
      for (int r = 0; r < 4; ++r) {
        int p = mte * 16 + quad * 4 + r;
        out[(((size_t)(i0 + (p >> 3))) * NRES + (j0 + (p & 7))) * CZ + e] =
            zacc[mte][nte][r] + bias;
      }
    }
}

// ---------------- host launch ----------------
extern "C" void kernel_launch(void* const* d_in, const int* in_sizes, int n_in,
                              void* d_out, int out_size, void* d_ws, size_t ws_size,
                              hipStream_t stream) {
  const float* m = (const float*)d_in[0];
  const float* gamma = (const float*)d_in[1];
  const float* beta = (const float*)d_in[2];
  const float* W1 = (const float*)d_in[3];
  const float* W2 = (const float*)d_in[4];
  const float* W3 = (const float*)d_in[5];
  const float* b3 = (const float*)d_in[6];
  float* out = (float*)d_out;

  unsigned short* aT = (unsigned short*)d_ws;                 // 12288 x 256 bf16
  unsigned short* bT = aT + (size_t)MDIM * S_DEPTH;           // 12288 x 256 bf16
  unsigned short* W3T = bT + (size_t)MDIM * S_DEPTH;          // 128 x 1024 bf16

  k_w3t<<<512, 256, 0, stream>>>(W3, W3T);
  k_lnproj<<<NRES, 256, 0, stream>>>(m, gamma, beta, W1, W2, aT, bT);
  k_opm<<<dim3(48, 96), 256, 0, stream>>>(aT, bT, W3T, b3, out);
}

// Round 3
// 345.131 us; speedup vs baseline: 1.2596x; 1.2596x over previous
//
#include <hip/hip_runtime.h>

#define S_DEPTH 256
#define NRES 384
#define CIN 32
#define CZ 128
#define MDIM (NRES * CIN) /* 12288 */

typedef short bf16x8 __attribute__((ext_vector_type(8)));
typedef short short4v __attribute__((ext_vector_type(4)));
typedef float f32x4 __attribute__((ext_vector_type(4)));

static __device__ __forceinline__ unsigned short f2bf(float f) {
  unsigned int u = __float_as_uint(f);
  unsigned int r = (u + 0x7fffu + ((u >> 16) & 1u)) >> 16; // RNE
  return (unsigned short)r;
}

static __device__ __forceinline__ void gld16(const void* g, void* l) {
  __builtin_amdgcn_global_load_lds((__attribute__((address_space(1))) void*)(g),
                                   (__attribute__((address_space(3))) void*)(l),
                                   16, 0, 0);
}

// ---------------- kernel 0: W3 -> bf16, layout W3T[e][d*32 + c] ----------------
__global__ __launch_bounds__(256) void k_w3t(const float* __restrict__ W3,
                                             unsigned short* __restrict__ W3T) {
  int t = blockIdx.x * 256 + threadIdx.x; // 0..131071
  int e = t >> 10;
  int q = t & 1023;    // q' = d*32 + c
  int d = q >> 5, c = q & 31;
  W3T[t] = f2bf(W3[(c * 32 + d) * 128 + e]);
}

// ---------------- kernel 1: LayerNorm + W1/W2 proj -> aT, bT (bf16, [m][k=s]) ----
// Thread t owns MSA row s=t. Direct transposed stores: for fixed c, lanes
// s..s+63 write 64 consecutive bf16 = 128 B contiguous -> coalesced. No
// transpose LDS phases, 1 barrier, ~40 live VGPRs (was ~100 -> spills).
__global__ __launch_bounds__(256) void k_lnproj(
    const float* __restrict__ mm, const float* __restrict__ gamma,
    const float* __restrict__ beta, const float* __restrict__ W1,
    const float* __restrict__ W2, unsigned short* __restrict__ aT,
    unsigned short* __restrict__ bT) {
  __shared__ float buf[256 * 33]; // stride 33 to break bank alignment
  const int t = threadIdx.x;
  const int i = blockIdx.x;

  // stage m[s][i][0:32] for all s, 16B per lane
#pragma unroll
  for (int it = 0; it < 8; ++it) {
    int s = it * 32 + (t >> 3);
    int c4 = (t & 7) * 4;
    const float4 v = *(const float4*)(mm + ((size_t)s * NRES + i) * CIN + c4);
    buf[s * 33 + c4 + 0] = v.x;
    buf[s * 33 + c4 + 1] = v.y;
    buf[s * 33 + c4 + 2] = v.z;
    buf[s * 33 + c4 + 3] = v.w;
  }
  __syncthreads();

  float x[32];
#pragma unroll
  for (int k = 0; k < 32; ++k) x[k] = buf[t * 33 + k];
  float mu = 0.f;
#pragma unroll
  for (int k = 0; k < 32; ++k) mu += x[k];
  mu *= (1.f / 32.f);
  float var = 0.f;
#pragma unroll
  for (int k = 0; k < 32; ++k) {
    float dk = x[k] - mu;
    var += dk * dk;
  }
  var *= (1.f / 32.f);
  float inv = rsqrtf(var + 1e-5f);
#pragma unroll
  for (int k = 0; k < 32; ++k) x[k] = (x[k] - mu) * inv * gamma[k] + beta[k];

  unsigned short* dstA = aT + (size_t)i * 32 * 256 + t;
#pragma unroll
  for (int c = 0; c < 32; ++c) {
    float sa = 0.f;
#pragma unroll
    for (int k = 0; k < 32; ++k) sa += x[k] * W1[k * 32 + c]; // uniform -> s_load
    dstA[c * 256] = f2bf(sa);
  }
  unsigned short* dstB = bT + (size_t)i * 32 * 256 + t;
#pragma unroll
  for (int c = 0; c < 32; ++c) {
    float sb = 0.f;
#pragma unroll
    for (int k = 0; k < 32; ++k) sb += x[k] * W2[k * 32 + c];
    dstB[c * 256] = f2bf(sb);
  }
}

// ---------------- kernel 2: fused o-GEMM (128x256 tile, BK=64) + W3 epilogue ----
// Main loop: global_load_lds (width 16) staging, tile-chunked LDS layout,
// BK=64 -> 4 k-steps, 8 barriers (halved vs R1). Epilogue: o repacked to
// bf16 in 64KB LDS (XOR-swizzled), then z = o * W3T with depth-2 W3T prefetch.
__global__ __launch_bounds__(256, 2) void k_opm(
    const unsigned short* __restrict__ aT, const unsigned short* __restrict__ bT,
    const unsigned short* __restrict__ W3T, const float* __restrict__ b3,
    float* __restrict__ out) {
  __shared__ __align__(16) char smem[65536];
  const int t = threadIdx.x;
  const int w = t >> 6;      // wave 0..3
  const int l = t & 63;      // lane
  const int lr = l & 15;
  const int quad = l >> 4;
  const int wm = w >> 1, wn = w & 1; // wave tile: rows wm*64, cols wn*128
  const int m0 = blockIdx.y * 128;   // i-block (4 residues)
  const int n0 = blockIdx.x * 256;   // j-block (8 residues)

  f32x4 acc[4][8];
#pragma unroll
  for (int mt = 0; mt < 4; ++mt)
#pragma unroll
    for (int nt = 0; nt < 8; ++nt) {
      acc[mt][nt][0] = 0.f; acc[mt][nt][1] = 0.f;
      acc[mt][nt][2] = 0.f; acc[mt][nt][3] = 0.f;
    }

  char* smemB = smem + 16384;

  // ---- main K loop, BK=64 ----
  // A-tile 128x64 = 16KB (16 chunks of 1KB), B-tile 256x64 = 32KB (32 chunks).
  // Chunk ch: tile=ch>>1, q=(ch&1)*4+(l>>4), r=l&15 ->
  //   global row = base + tile*16 + r, k = k0 + q*8; LDS = ch*1024 (+l*16 impl.)
  for (int k0 = 0; k0 < 256; k0 += 64) {
    __syncthreads();
#pragma unroll
    for (int p_ = 0; p_ < 4; ++p_) {
      int ch = p_ * 4 + w;
      gld16(aT + (size_t)(m0 + (ch >> 1) * 16 + lr) * 256 + k0 + ((ch & 1) * 4 + quad) * 8,
            smem + ch * 1024);
    }
#pragma unroll
    for (int p_ = 0; p_ < 8; ++p_) {
      int ch = p_ * 4 + w;
      gld16(bT + (size_t)(n0 + (ch >> 1) * 16 + lr) * 256 + k0 + ((ch & 1) * 4 + quad) * 8,
            smemB + ch * 1024);
    }
    __syncthreads();

#pragma unroll
    for (int ks = 0; ks < 2; ++ks) {
      bf16x8 af[4];
#pragma unroll
      for (int mt = 0; mt < 4; ++mt)
        af[mt] = *(const bf16x8*)(smem + (wm * 4 + mt) * 2048 + (ks * 4 + quad) * 256 + lr * 16);
#pragma unroll
      for (int nt = 0; nt < 8; ++nt) {
        bf16x8 bfr = *(const bf16x8*)(smemB + (wn * 8 + nt) * 2048 + (ks * 4 + quad) * 256 + lr * 16);
#pragma unroll
        for (int mt = 0; mt < 4; ++mt)
          acc[mt][nt] =
              __builtin_amdgcn_mfma_f32_16x16x32_bf16(af[mt], bfr, acc[mt][nt], 0, 0, 0);
      }
    }
  }

  // ---- epilogue: repack o (bf16, /256) into o_lds[32 pairs][1024 q'] with
  // XOR chunk swizzle key=(p^d)&7 ----
  __syncthreads();
  const float scale = 1.0f / 256.0f;
#pragma unroll
  for (int mt = 0; mt < 4; ++mt) {
    int i_l = wm * 2 + (mt >> 1);
    int chc = 2 * (mt & 1) + (quad >> 1); // (c0>>3)
#pragma unroll
    for (int nt = 0; nt < 8; ++nt) {
      int j_l = wn * 4 + (nt >> 1);
      int d = (nt & 1) * 16 + lr;
      int p = i_l * 8 + j_l;
      int ch = d * 4 + chc;
      int key = (p ^ d) & 7;
      int off = p * 2048 + ((ch ^ key) << 4) + 8 * (quad & 1); // bytes
      short4v pk;
      pk[0] = (short)f2bf(acc[mt][nt][0] * scale);
      pk[1] = (short)f2bf(acc[mt][nt][1] * scale);
      pk[2] = (short)f2bf(acc[mt][nt][2] * scale);
      pk[3] = (short)f2bf(acc[mt][nt][3] * scale);
      *(short4v*)(smem + off) = pk;
    }
  }
  __syncthreads();

  // ---- z[p][e] = sum_q o[p][q'] * W3T[e][q'] ; wave w owns e-tiles {2w,2w+1}
  f32x4 zacc[2][2];
#pragma unroll
  for (int a = 0; a < 2; ++a)
#pragma unroll
    for (int b = 0; b < 2; ++b) {
      zacc[a][b][0] = 0.f; zacc[a][b][1] = 0.f;
      zacc[a][b][2] = 0.f; zacc[a][b][3] = 0.f;
    }
  float bias0 = b3[(w * 2 + 0) * 16 + lr];
  float bias1 = b3[(w * 2 + 1) * 16 + lr];

  const unsigned short* wg0 = W3T + (size_t)((w * 2 + 0) * 16 + lr) * 1024 + quad * 8;
  const unsigned short* wg1 = W3T + (size_t)((w * 2 + 1) * 16 + lr) * 1024 + quad * 8;

  // depth-2 software prefetch of W3T B-frags (global, L2-hot)
  bf16x8 wcur0 = *(const bf16x8*)(wg0);
  bf16x8 wcur1 = *(const bf16x8*)(wg1);
#pragma unroll
  for (int kq = 0; kq < 32; ++kq) {
    bf16x8 wnxt0, wnxt1;
    if (kq < 31) {
      wnxt0 = *(const bf16x8*)(wg0 + (kq + 1) * 32);
      wnxt1 = *(const bf16x8*)(wg1 + (kq + 1) * 32);
    }
    bf16x8 aef[2];
#pragma unroll
    for (int mte = 0; mte < 2; ++mte) {
      int row = mte * 16 + lr;
      int ch = kq * 4 + quad;
      int key = (row ^ kq) & 7;
      aef[mte] = *(const bf16x8*)(smem + row * 2048 + ((ch ^ key) << 4));
    }
    zacc[0][0] = __builtin_amdgcn_mfma_f32_16x16x32_bf16(aef[0], wcur0, zacc[0][0], 0, 0, 0);
    zacc[1][0] = __builtin_amdgcn_mfma_f32_16x16x32_bf16(aef[1], wcur0, zacc[1][0], 0, 0, 0);
    zacc[0][1] = __builtin_amdgcn_mfma_f32_16x16x32_bf16(aef[0], wcur1, zacc[0][1], 0, 0, 0);
    zacc[1][1] = __builtin_amdgcn_mfma_f32_16x16x32_bf16(aef[1], wcur1, zacc[1][1], 0, 0, 0);
    wcur0 = wnxt0;
    wcur1 = wnxt1;
  }

  const int i0 = blockIdx.y * 4, j0 = blockIdx.x * 8;
#pragma unroll
  for (int mte = 0; mte < 2; ++mte)
#pragma unroll
    for (int nte = 0; nte < 2; ++nte) {
      int e = (w * 2 + nte) * 16 + lr;
      float bias = nte ? bias1 : bias0;
#pragma unroll
      for (int r = 0; r < 4; ++r) {
        int p = mte * 16 + quad * 4 + r;
        out[(((size_t)(i0 + (p >> 3))) * NRES + (j0 + (p & 7))) * CZ + e] =
            zacc[mte][nte][r] + bias;
      }
    }
}

// ---------------- host launch ----------------
extern "C" void kernel_launch(void* const* d_in, const int* in_sizes, int n_in,
                              void* d_out, int out_size, void* d_ws, size_t ws_size,
                              hipStream_t stream) {
  const float* m = (const float*)d_in[0];
  const float* gamma = (const float*)d_in[1];
  const float* beta = (const float*)d_in[2];
  const float* W1 = (const float*)d_in[3];
  const float* W2 = (const float*)d_in[4];
  const float* W3 = (const float*)d_in[5];
  const float* b3 = (const float*)d_in[6];
  float* out = (float*)d_out;

  unsigned short* aT = (unsigned short*)d_ws;                 // 12288 x 256 bf16
  unsigned short* bT = aT + (size_t)MDIM * S_DEPTH;           // 12288 x 256 bf16
  unsigned short* W3T = bT + (size_t)MDIM * S_DEPTH;          // 128 x 1024 bf16

  k_w3t<<<512, 256, 0, stream>>>(W3, W3T);
  k_lnproj<<<NRES, 256, 0, stream>>>(m, gamma, beta, W1, W2, aT, bT);
  k_opm<<<dim3(48, 96), 256, 0, stream>>>(aT, bT, W3T, b3, out);
}

// Round 4
// 245.141 us; speedup vs baseline: 1.7734x; 1.4079x over previous
//
#include <hip/hip_runtime.h>

#define S_DEPTH 256
#define NRES 384
#define CIN 32
#define CZ 128
#define MDIM (NRES * CIN) /* 12288 */

typedef short bf16x8 __attribute__((ext_vector_type(8)));
typedef short short4v __attribute__((ext_vector_type(4)));
typedef float f32x4 __attribute__((ext_vector_type(4)));

static __device__ __forceinline__ unsigned short f2bf(float f) {
  unsigned int u = __float_as_uint(f);
  unsigned int r = (u + 0x7fffu + ((u >> 16) & 1u)) >> 16; // RNE
  return (unsigned short)r;
}

static __device__ __forceinline__ void gld16(const void* g, void* l) {
  __builtin_amdgcn_global_load_lds((__attribute__((address_space(1))) void*)(g),
                                   (__attribute__((address_space(3))) void*)(l),
                                   16, 0, 0);
}

// ---------------- fused pre-kernel ----------------
// blocks 0..15:  W3 (fp32 [1024 q][128 e], q=c*32+d) -> W3T bf16, kq-major:
//                W3T[(kq*128 + e)*32 + j] = bf16(W3[q][e]), q' = d*32+c = kq*32+j
// blocks 16..399: LayerNorm + W1/W2 proj for residue i = blk-16 ->
//                aT/bT bf16, k-slice-major: aT[((s>>6)*12288 + i*32+c)*64 + (s&63)]
__global__ __launch_bounds__(256) void k_pre(
    const float* __restrict__ mm, const float* __restrict__ gamma,
    const float* __restrict__ beta, const float* __restrict__ W1,
    const float* __restrict__ W2, const float* __restrict__ W3,
    unsigned short* __restrict__ aT, unsigned short* __restrict__ bT,
    unsigned short* __restrict__ W3T) {
  __shared__ __align__(16) char sraw[256 * 33 * 4];
  const int t = threadIdx.x;

  if (blockIdx.x < 16) {
    // ---- W3 transpose tile: d0 = (b&7)*4 (4 d values), e-half = b>>3 ----
    unsigned short (*tile)[72] = (unsigned short(*)[72])sraw; // [128][72]
    const int b = blockIdx.x;
    const int d0 = (b & 7) * 4;
    const int e0 = (b >> 3) * 64;
    // phase 1: read 128 rows (q = c*32 + d0+dl, local row lr_ = c*4+dl) x 64 e
#pragma unroll
    for (int iter = 0; iter < 32; ++iter) {
      int lr_ = iter * 4 + (t >> 6);
      int c = lr_ >> 2, dl = lr_ & 3;
      int q = c * 32 + d0 + dl;
      tile[lr_][t & 63] = f2bf(W3[q * 128 + e0 + (t & 63)]);
    }
    __syncthreads();
    // phase 2: thread t writes 32 contiguous ushort: kq = d0+(t&3), e = e0+(t>>2)
    const int e_l = t >> 2;
    const int dl = t & 3;
    unsigned short* dst = W3T + (((size_t)(d0 + dl) * 128) + e0 + e_l) * 32;
#pragma unroll
    for (int j = 0; j < 32; ++j) dst[j] = tile[j * 4 + dl][e_l];
    return;
  }

  // ---- LayerNorm + projections, residue i ----
  float* buf = (float*)sraw; // [256][33]
  const int i = blockIdx.x - 16;

#pragma unroll
  for (int it = 0; it < 8; ++it) {
    int s = it * 32 + (t >> 3);
    int c4 = (t & 7) * 4;
    const float4 v = *(const float4*)(mm + ((size_t)s * NRES + i) * CIN + c4);
    buf[s * 33 + c4 + 0] = v.x;
    buf[s * 33 + c4 + 1] = v.y;
    buf[s * 33 + c4 + 2] = v.z;
    buf[s * 33 + c4 + 3] = v.w;
  }
  __syncthreads();

  float x[32];
#pragma unroll
  for (int k = 0; k < 32; ++k) x[k] = buf[t * 33 + k];
  float mu = 0.f;
#pragma unroll
  for (int k = 0; k < 32; ++k) mu += x[k];
  mu *= (1.f / 32.f);
  float var = 0.f;
#pragma unroll
  for (int k = 0; k < 32; ++k) {
    float dk = x[k] - mu;
    var += dk * dk;
  }
  var *= (1.f / 32.f);
  float inv = rsqrtf(var + 1e-5f);
#pragma unroll
  for (int k = 0; k < 32; ++k) x[k] = (x[k] - mu) * inv * gamma[k] + beta[k];

  float va[32], vb[32];
#pragma unroll
  for (int c = 0; c < 32; ++c) { va[c] = 0.f; vb[c] = 0.f; }
  // k-outer: W rows load as wide uniform s_loads, no scalar dependency chain
#pragma unroll
  for (int k = 0; k < 32; ++k) {
    float xk = x[k];
#pragma unroll
    for (int c = 0; c < 32; ++c) va[c] += xk * W1[k * 32 + c];
#pragma unroll
    for (int c = 0; c < 32; ++c) vb[c] += xk * W2[k * 32 + c];
  }

  // k-slice-major stores: per c, wave writes 64 consecutive ushort (128B)
  unsigned short* dstA = aT + ((size_t)(t >> 6) * MDIM + (size_t)i * 32) * 64 + (t & 63);
  unsigned short* dstB = bT + ((size_t)(t >> 6) * MDIM + (size_t)i * 32) * 64 + (t & 63);
#pragma unroll
  for (int c = 0; c < 32; ++c) dstA[c * 64] = f2bf(va[c]);
#pragma unroll
  for (int c = 0; c < 32; ++c) dstB[c * 64] = f2bf(vb[c]);
}

// ---------------- kernel 2: fused o-GEMM (128x256 tile, BK=64) + W3 epilogue ----
// XCD-aware 1D grid: xcd = g&7; per-XCD 48(bx) x 12(by_l) sub-grid, 12
// consecutive blocks share one bT stripe -> staging hits per-XCD L2.
// Staging: k-slice-major, each gld16 = 1KB fully contiguous; XOR k-seg
// swizzle (seg' = seg ^ row) folded into the GLOBAL read order so LDS
// frag reads are conflict-free under the rigid lane*16 DMA scatter.
__global__ __launch_bounds__(256, 2) void k_opm(
    const unsigned short* __restrict__ aT, const unsigned short* __restrict__ bT,
    const unsigned short* __restrict__ W3T, const float* __restrict__ b3,
    float* __restrict__ out) {
  __shared__ __align__(16) char smem[65536];
  const int t = threadIdx.x;
  const int w = t >> 6;      // wave 0..3
  const int l = t & 63;      // lane
  const int lr = l & 15;
  const int quad = l >> 4;
  const int wm = w >> 1, wn = w & 1;

  const int g = blockIdx.x;
  const int xcd = g & 7;
  const int r = g >> 3;            // 0..575
  const int bx = r / 12;           // 0..47 : n-stripe, shared by 12 consecutive
  const int by = xcd * 12 + (r - bx * 12); // 0..95
  const int m0 = by * 128;
  const int n0 = bx * 256;

  f32x4 acc[4][8];
#pragma unroll
  for (int mt = 0; mt < 4; ++mt)
#pragma unroll
    for (int nt = 0; nt < 8; ++nt) {
      acc[mt][nt][0] = 0.f; acc[mt][nt][1] = 0.f;
      acc[mt][nt][2] = 0.f; acc[mt][nt][3] = 0.f;
    }

  char* smemB = smem + 16384;
  // lane's global offset within a 1KB chunk: row (l>>3), k-seg (l&7)^(l>>3)
  const int laneoff = (l >> 3) * 64 + (((l & 7) ^ (l >> 3)) * 8);

  for (int k0 = 0; k0 < 256; k0 += 64) {
    __syncthreads();
    const unsigned short* aSlab = aT + ((size_t)(k0 >> 6) * MDIM + m0) * 64;
    const unsigned short* bSlab = bT + ((size_t)(k0 >> 6) * MDIM + n0) * 64;
#pragma unroll
    for (int p_ = 0; p_ < 4; ++p_) {
      int ch = p_ * 4 + w;
      gld16(aSlab + ch * 512 + laneoff, smem + ch * 1024);
    }
#pragma unroll
    for (int p_ = 0; p_ < 8; ++p_) {
      int ch = p_ * 4 + w;
      gld16(bSlab + ch * 512 + laneoff, smemB + ch * 1024);
    }
    __syncthreads();

#pragma unroll
    for (int ks = 0; ks < 2; ++ks) {
      const int r8 = lr & 7;
      const int segoff = (((ks * 4 + quad) ^ r8) << 4);
      bf16x8 af[4];
#pragma unroll
      for (int mt = 0; mt < 4; ++mt) {
        int chunk = (wm * 4 + mt) * 2 + (lr >> 3);
        af[mt] = *(const bf16x8*)(smem + chunk * 1024 + r8 * 128 + segoff);
      }
#pragma unroll
      for (int nt = 0; nt < 8; ++nt) {
        int chunk = (wn * 8 + nt) * 2 + (lr >> 3);
        bf16x8 bfr = *(const bf16x8*)(smemB + chunk * 1024 + r8 * 128 + segoff);
#pragma unroll
        for (int mt = 0; mt < 4; ++mt)
          acc[mt][nt] =
              __builtin_amdgcn_mfma_f32_16x16x32_bf16(af[mt], bfr, acc[mt][nt], 0, 0, 0);
      }
    }
  }

  // ---- epilogue: repack o (bf16, /256) into o_lds[32 p][1024 q'] XOR-swizzled
  __syncthreads();
  const float scale = 1.0f / 256.0f;
#pragma unroll
  for (int mt = 0; mt < 4; ++mt) {
    int i_l = wm * 2 + (mt >> 1);
    int chc = 2 * (mt & 1) + (quad >> 1);
#pragma unroll
    for (int nt = 0; nt < 8; ++nt) {
      int j_l = wn * 4 + (nt >> 1);
      int d = (nt & 1) * 16 + lr;
      int p = i_l * 8 + j_l;
      int ch = d * 4 + chc;
      int key = (p ^ d) & 7;
      int off = p * 2048 + ((ch ^ key) << 4) + 8 * (quad & 1);
      short4v pk;
      pk[0] = (short)f2bf(acc[mt][nt][0] * scale);
      pk[1] = (short)f2bf(acc[mt][nt][1] * scale);
      pk[2] = (short)f2bf(acc[mt][nt][2] * scale);
      pk[3] = (short)f2bf(acc[mt][nt][3] * scale);
      *(short4v*)(smem + off) = pk;
    }
  }
  __syncthreads();

  // ---- z[p][e] = sum_q' o[p][q'] * W3T_k[kq][e][j] ----
  f32x4 zacc[2][2];
#pragma unroll
  for (int a = 0; a < 2; ++a)
#pragma unroll
    for (int b = 0; b < 2; ++b) {
      zacc[a][b][0] = 0.f; zacc[a][b][1] = 0.f;
      zacc[a][b][2] = 0.f; zacc[a][b][3] = 0.f;
    }
  float bias0 = b3[(w * 2 + 0) * 16 + lr];
  float bias1 = b3[(w * 2 + 1) * 16 + lr];

  // kq-major W3T: frag ptr = W3T + (kq*128 + e)*32 + quad*8 ; kq step = 4096
  const unsigned short* wg0 = W3T + (size_t)((w * 2 + 0) * 16 + lr) * 32 + quad * 8;
  const unsigned short* wg1 = wg0 + 16 * 32;

  bf16x8 wcur0 = *(const bf16x8*)(wg0);
  bf16x8 wcur1 = *(const bf16x8*)(wg1);
#pragma unroll
  for (int kq = 0; kq < 32; ++kq) {
    bf16x8 wnxt0, wnxt1;
    if (kq < 31) {
      wnxt0 = *(const bf16x8*)(wg0 + (size_t)(kq + 1) * 4096);
      wnxt1 = *(const bf16x8*)(wg1 + (size_t)(kq + 1) * 4096);
    }
    bf16x8 aef[2];
#pragma unroll
    for (int mte = 0; mte < 2; ++mte) {
      int row = mte * 16 + lr;
      int ch = kq * 4 + quad;
      int key = (row ^ kq) & 7;
      aef[mte] = *(const bf16x8*)(smem + row * 2048 + ((ch ^ key) << 4));
    }
    zacc[0][0] = __builtin_amdgcn_mfma_f32_16x16x32_bf16(aef[0], wcur0, zacc[0][0], 0, 0, 0);
    zacc[1][0] = __builtin_amdgcn_mfma_f32_16x16x32_bf16(aef[1], wcur0, zacc[1][0], 0, 0, 0);
    zacc[0][1] = __builtin_amdgcn_mfma_f32_16x16x32_bf16(aef[0], wcur1, zacc[0][1], 0, 0, 0);
    zacc[1][1] = __builtin_amdgcn_mfma_f32_16x16x32_bf16(aef[1], wcur1, zacc[1][1], 0, 0, 0);
    wcur0 = wnxt0;
    wcur1 = wnxt1;
  }

  const int i0 = by * 4, j0 = bx * 8;
#pragma unroll
  for (int mte = 0; mte < 2; ++mte)
#pragma unroll
    for (int nte = 0; nte < 2; ++nte) {
      int e = (w * 2 + nte) * 16 + lr;
      float bias = nte ? bias1 : bias0;
#pragma unroll
      for (int rr = 0; rr < 4; ++rr) {
        int p = mte * 16 + quad * 4 + rr;
        out[(((size_t)(i0 + (p >> 3))) * NRES + (j0 + (p & 7))) * CZ + e] =
            zacc[mte][nte][rr] + bias;
      }
    }
}

// ---------------- host launch ----------------
extern "C" void kernel_launch(void* const* d_in, const int* in_sizes, int n_in,
                              void* d_out, int out_size, void* d_ws, size_t ws_size,
                              hipStream_t stream) {
  const float* m = (const float*)d_in[0];
  const float* gamma = (const float*)d_in[1];
  const float* beta = (const float*)d_in[2];
  const float* W1 = (const float*)d_in[3];
  const float* W2 = (const float*)d_in[4];
  const float* W3 = (const float*)d_in[5];
  const float* b3 = (const float*)d_in[6];
  float* out = (float*)d_out;

  unsigned short* aT = (unsigned short*)d_ws;                 // 12288 x 256 bf16 (k-slice-major)
  unsigned short* bT = aT + (size_t)MDIM * S_DEPTH;           // 12288 x 256 bf16
  unsigned short* W3T = bT + (size_t)MDIM * S_DEPTH;          // 32 x 128 x 32 bf16 (kq-major)

  k_pre<<<400, 256, 0, stream>>>(m, gamma, beta, W1, W2, W3, aT, bT, W3T);
  k_opm<<<4608, 256, 0, stream>>>(aT, bT, W3T, b3, out);
}

// Round 5
// 236.609 us; speedup vs baseline: 1.8374x; 1.0361x over previous
//
#include <hip/hip_runtime.h>

#define S_DEPTH 256
#define NRES 384
#define CIN 32
#define CZ 128
#define MDIM (NRES * CIN) /* 12288 */

typedef short bf16x8 __attribute__((ext_vector_type(8)));
typedef short short4v __attribute__((ext_vector_type(4)));
typedef float f32x4 __attribute__((ext_vector_type(4)));

static __device__ __forceinline__ unsigned short f2bf(float f) {
  unsigned int u = __float_as_uint(f);
  unsigned int r = (u + 0x7fffu + ((u >> 16) & 1u)) >> 16; // RNE
  return (unsigned short)r;
}

static __device__ __forceinline__ void gld16(const void* g, void* l) {
  __builtin_amdgcn_global_load_lds((__attribute__((address_space(1))) void*)(g),
                                   (__attribute__((address_space(3))) void*)(l),
                                   16, 0, 0);
}

// ---------------- fused pre-kernel (unchanged from R4) ----------------
__global__ __launch_bounds__(256) void k_pre(
    const float* __restrict__ mm, const float* __restrict__ gamma,
    const float* __restrict__ beta, const float* __restrict__ W1,
    const float* __restrict__ W2, const float* __restrict__ W3,
    unsigned short* __restrict__ aT, unsigned short* __restrict__ bT,
    unsigned short* __restrict__ W3T) {
  __shared__ __align__(16) char sraw[256 * 33 * 4];
  const int t = threadIdx.x;

  if (blockIdx.x < 16) {
    unsigned short (*tile)[72] = (unsigned short(*)[72])sraw; // [128][72]
    const int b = blockIdx.x;
    const int d0 = (b & 7) * 4;
    const int e0 = (b >> 3) * 64;
#pragma unroll
    for (int iter = 0; iter < 32; ++iter) {
      int lr_ = iter * 4 + (t >> 6);
      int c = lr_ >> 2, dl = lr_ & 3;
      int q = c * 32 + d0 + dl;
      tile[lr_][t & 63] = f2bf(W3[q * 128 + e0 + (t & 63)]);
    }
    __syncthreads();
    const int e_l = t >> 2;
    const int dl = t & 3;
    unsigned short* dst = W3T + (((size_t)(d0 + dl) * 128) + e0 + e_l) * 32;
#pragma unroll
    for (int j = 0; j < 32; ++j) dst[j] = tile[j * 4 + dl][e_l];
    return;
  }

  float* buf = (float*)sraw; // [256][33]
  const int i = blockIdx.x - 16;

#pragma unroll
  for (int it = 0; it < 8; ++it) {
    int s = it * 32 + (t >> 3);
    int c4 = (t & 7) * 4;
    const float4 v = *(const float4*)(mm + ((size_t)s * NRES + i) * CIN + c4);
    buf[s * 33 + c4 + 0] = v.x;
    buf[s * 33 + c4 + 1] = v.y;
    buf[s * 33 + c4 + 2] = v.z;
    buf[s * 33 + c4 + 3] = v.w;
  }
  __syncthreads();

  float x[32];
#pragma unroll
  for (int k = 0; k < 32; ++k) x[k] = buf[t * 33 + k];
  float mu = 0.f;
#pragma unroll
  for (int k = 0; k < 32; ++k) mu += x[k];
  mu *= (1.f / 32.f);
  float var = 0.f;
#pragma unroll
  for (int k = 0; k < 32; ++k) {
    float dk = x[k] - mu;
    var += dk * dk;
  }
  var *= (1.f / 32.f);
  float inv = rsqrtf(var + 1e-5f);
#pragma unroll
  for (int k = 0; k < 32; ++k) x[k] = (x[k] - mu) * inv * gamma[k] + beta[k];

  float va[32], vb[32];
#pragma unroll
  for (int c = 0; c < 32; ++c) { va[c] = 0.f; vb[c] = 0.f; }
#pragma unroll
  for (int k = 0; k < 32; ++k) {
    float xk = x[k];
#pragma unroll
    for (int c = 0; c < 32; ++c) va[c] += xk * W1[k * 32 + c];
#pragma unroll
    for (int c = 0; c < 32; ++c) vb[c] += xk * W2[k * 32 + c];
  }

  unsigned short* dstA = aT + ((size_t)(t >> 6) * MDIM + (size_t)i * 32) * 64 + (t & 63);
  unsigned short* dstB = bT + ((size_t)(t >> 6) * MDIM + (size_t)i * 32) * 64 + (t & 63);
#pragma unroll
  for (int c = 0; c < 32; ++c) dstA[c * 64] = f2bf(va[c]);
#pragma unroll
  for (int c = 0; c < 32; ++c) dstB[c * 64] = f2bf(vb[c]);
}

// ---------------- kernel 2: 256x256 o-tile, 512 threads, fused W3 epilogue ----
// 8 waves: wave tile 128x64 (wm=w>>2 rows, wn=w&3 cols). Per-block cache
// traffic: 256KB staging + 256KB W3T + 32KB out over 65536 o-elems
// (8.3 B/elem vs 14.2 at 128x256). XCD pins 6 by-rows -> aT set L2-resident.
__global__ __launch_bounds__(512, 2) void k_opm(
    const unsigned short* __restrict__ aT, const unsigned short* __restrict__ bT,
    const unsigned short* __restrict__ W3T, const float* __restrict__ b3,
    float* __restrict__ out) {
  __shared__ __align__(16) char smem[131072]; // staging 64KB; o_lds 128KB
  const int t = threadIdx.x;
  const int w = t >> 6;      // wave 0..7
  const int l = t & 63;
  const int lr = l & 15;
  const int quad = l >> 4;
  const int wm = w >> 2, wn = w & 3;

  const int g = blockIdx.x;
  const int xcd = g & 7;
  const int rr = g >> 3;           // 0..287
  const int bx = rr / 6;           // 0..47
  const int by = xcd * 6 + (rr - bx * 6); // 0..47
  const int m0 = by * 256;
  const int n0 = bx * 256;

  f32x4 acc[8][4];
#pragma unroll
  for (int mt = 0; mt < 8; ++mt)
#pragma unroll
    for (int nt = 0; nt < 4; ++nt) {
      acc[mt][nt][0] = 0.f; acc[mt][nt][1] = 0.f;
      acc[mt][nt][2] = 0.f; acc[mt][nt][3] = 0.f;
    }

  char* smemB = smem + 32768;
  // lane offset inside a 1KB chunk (8 rows x 128B), XOR k-seg swizzle
  const int laneoff = (l >> 3) * 64 + (((l & 7) ^ (l >> 3)) * 8);
  const int r8 = lr & 7;

  for (int k0 = 0; k0 < 256; k0 += 64) {
    __syncthreads();
    const unsigned short* aSlab = aT + ((size_t)(k0 >> 6) * MDIM + m0) * 64;
    const unsigned short* bSlab = bT + ((size_t)(k0 >> 6) * MDIM + n0) * 64;
#pragma unroll
    for (int p_ = 0; p_ < 4; ++p_) {
      int ch = p_ * 8 + w;
      gld16(aSlab + ch * 512 + laneoff, smem + ch * 1024);
    }
#pragma unroll
    for (int p_ = 0; p_ < 4; ++p_) {
      int ch = p_ * 8 + w;
      gld16(bSlab + ch * 512 + laneoff, smemB + ch * 1024);
    }
    __syncthreads();

#pragma unroll
    for (int ks = 0; ks < 2; ++ks) {
      const int segoff = (((ks * 4 + quad) ^ r8) << 4);
      bf16x8 af[8];
#pragma unroll
      for (int mt = 0; mt < 8; ++mt) {
        int chunk = wm * 16 + mt * 2 + (lr >> 3);
        af[mt] = *(const bf16x8*)(smem + chunk * 1024 + r8 * 128 + segoff);
      }
#pragma unroll
      for (int nt = 0; nt < 4; ++nt) {
        int chunk = wn * 8 + nt * 2 + (lr >> 3);
        bf16x8 bfr = *(const bf16x8*)(smemB + chunk * 1024 + r8 * 128 + segoff);
#pragma unroll
        for (int mt = 0; mt < 8; ++mt)
          acc[mt][nt] =
              __builtin_amdgcn_mfma_f32_16x16x32_bf16(af[mt], bfr, acc[mt][nt], 0, 0, 0);
      }
    }
  }

  // ---- repack o (bf16, /256) into o_lds[64 p][1024 q'] XOR-swizzled ----
  __syncthreads();
  const float scale = 1.0f / 256.0f;
#pragma unroll
  for (int mt = 0; mt < 8; ++mt) {
    int i_l = wm * 4 + (mt >> 1);
    int chc = 2 * (mt & 1) + (quad >> 1); // c0>>3, c0 = (mt&1)*16 + quad*4
#pragma unroll
    for (int nt = 0; nt < 4; ++nt) {
      int j_l = wn * 2 + (nt >> 1);
      int d = (nt & 1) * 16 + lr;
      int p = i_l * 8 + j_l;
      int ch = d * 4 + chc;
      int key = (p ^ d) & 7;
      int off = p * 2048 + ((ch ^ key) << 4) + 8 * (quad & 1);
      short4v pk;
      pk[0] = (short)f2bf(acc[mt][nt][0] * scale);
      pk[1] = (short)f2bf(acc[mt][nt][1] * scale);
      pk[2] = (short)f2bf(acc[mt][nt][2] * scale);
      pk[3] = (short)f2bf(acc[mt][nt][3] * scale);
      *(short4v*)(smem + off) = pk;
    }
  }
  __syncthreads();

  // ---- z[p][e] = sum_q' o[p][q'] * W3T ; wave w owns e-tile w (16 e) ----
  f32x4 zacc[4];
#pragma unroll
  for (int a = 0; a < 4; ++a) {
    zacc[a][0] = 0.f; zacc[a][1] = 0.f; zacc[a][2] = 0.f; zacc[a][3] = 0.f;
  }
  const float bias = b3[w * 16 + lr];

  // kq-major W3T: frag = W3T + (kq*128 + e)*32 + quad*8 ; kq step 4096 shorts
  const unsigned short* wg = W3T + (size_t)(w * 16 + lr) * 32 + quad * 8;

  bf16x8 wcur = *(const bf16x8*)(wg);
#pragma unroll
  for (int kq = 0; kq < 32; ++kq) {
    bf16x8 wnxt;
    if (kq < 31) wnxt = *(const bf16x8*)(wg + (size_t)(kq + 1) * 4096);
    bf16x8 aef[4];
#pragma unroll
    for (int mte = 0; mte < 4; ++mte) {
      int row = mte * 16 + lr;
      int ch = kq * 4 + quad;
      int key = (row ^ kq) & 7;
      aef[mte] = *(const bf16x8*)(smem + row * 2048 + ((ch ^ key) << 4));
    }
#pragma unroll
    for (int mte = 0; mte < 4; ++mte)
      zacc[mte] = __builtin_amdgcn_mfma_f32_16x16x32_bf16(aef[mte], wcur, zacc[mte], 0, 0, 0);
    wcur = wnxt;
  }

  const int i0 = by * 8, j0 = bx * 8;
  const int e = w * 16 + lr;
#pragma unroll
  for (int mte = 0; mte < 4; ++mte)
#pragma unroll
    for (int r = 0; r < 4; ++r) {
      int p = mte * 16 + quad * 4 + r;
      out[(((size_t)(i0 + (p >> 3))) * NRES + (j0 + (p & 7))) * CZ + e] =
          zacc[mte][r] + bias;
    }
}

// ---------------- host launch ----------------
extern "C" void kernel_launch(void* const* d_in, const int* in_sizes, int n_in,
                              void* d_out, int out_size, void* d_ws, size_t ws_size,
                              hipStream_t stream) {
  const float* m = (const float*)d_in[0];
  const float* gamma = (const float*)d_in[1];
  const float* beta = (const float*)d_in[2];
  const float* W1 = (const float*)d_in[3];
  const float* W2 = (const float*)d_in[4];
  const float* W3 = (const float*)d_in[5];
  const float* b3 = (const float*)d_in[6];
  float* out = (float*)d_out;

  unsigned short* aT = (unsigned short*)d_ws;                 // k-slice-major
  unsigned short* bT = aT + (size_t)MDIM * S_DEPTH;
  unsigned short* W3T = bT + (size_t)MDIM * S_DEPTH;          // kq-major

  k_pre<<<400, 256, 0, stream>>>(m, gamma, beta, W1, W2, W3, aT, bT, W3T);
  k_opm<<<2304, 512, 0, stream>>>(aT, bT, W3T, b3, out);
}